// Round 1
// 141.140 us; speedup vs baseline: 1.0074x; 1.0074x over previous
//
#include <hip/hip_runtime.h>

#define LDSP 136  // padded row stride; 272B rows -> 4-bank rotation per row, b128 reads conflict-minimal

typedef _Float16 h8 __attribute__((ext_vector_type(8)));
typedef _Float16 h4 __attribute__((ext_vector_type(4)));
typedef float    f4 __attribute__((ext_vector_type(4)));

// ---- fused prep: Mt[f][e] = sum_d Wk[d][f]*Wq[d][e] (f16), ck[f] = sum_d bq[d]*Wk[d][f] ----
// softmax(QK^T) == softmax(X Mt^T X^T + 1 * (ck . X^T)) -- row-constant terms drop.
// 64 blocks x 256 threads. 4-way ILP-split accumulators break the dependent-FMA chain.
__global__ void prep(const float* __restrict__ Wq, const float* __restrict__ Wk,
                     const float* __restrict__ bq, _Float16* __restrict__ Mt,
                     float* __restrict__ ck) {
    int idx = blockIdx.x * 256 + threadIdx.x;  // 16384 entries
    int e = idx & 127, f = idx >> 7;
    float a0 = 0.f, a1 = 0.f, a2 = 0.f, a3 = 0.f;
    for (int d = 0; d < 128; d += 4) {
        a0 += Wk[(d + 0) * 128 + f] * Wq[(d + 0) * 128 + e];  // Wk broadcast per wave; Wq coalesced
        a1 += Wk[(d + 1) * 128 + f] * Wq[(d + 1) * 128 + e];
        a2 += Wk[(d + 2) * 128 + f] * Wq[(d + 2) * 128 + e];
        a3 += Wk[(d + 3) * 128 + f] * Wq[(d + 3) * 128 + e];
    }
    Mt[idx] = (_Float16)((a0 + a1) + (a2 + a3));

    if (blockIdx.x == 0 && threadIdx.x < 128) {
        int t = threadIdx.x;
        float c0 = 0.f, c1 = 0.f, c2 = 0.f, c3 = 0.f;
        for (int d = 0; d < 128; d += 4) {
            c0 += bq[d + 0] * Wk[(d + 0) * 128 + t];
            c1 += bq[d + 1] * Wk[(d + 1) * 128 + t];
            c2 += bq[d + 2] * Wk[(d + 2) * 128 + t];
            c3 += bq[d + 3] * Wk[(d + 3) * 128 + t];
        }
        ck[t] = (c0 + c1) + (c2 + c3);
    }
}

// One persistent block per CU; each handles 4 consecutive windows, prefetching
// the next window's X into registers while computing the current one.
// Wv is read directly as f32 (L2/L3-resident, 128B/thread once) and converted
// in-register -- no Wvh staging buffer / prep pass needed.
__global__ __launch_bounds__(512, 2) void attn(
    const float* __restrict__ x, const _Float16* __restrict__ Mt,
    const float* __restrict__ Wv, const float* __restrict__ ck,
    const float* __restrict__ bv, float* __restrict__ out) {
    __shared__ _Float16 Xs[2][128 * LDSP];  // double-buffered X (f16)
    __shared__ _Float16 Ts[128 * LDSP];     // T'[w][f]; own-strip rows reused as P[w][u]
    __shared__ _Float16 Vs[128 * LDSP];     // V transposed: Vs[d][u]

    const int tid  = threadIdx.x;
    const int wave = tid >> 6;
    const int lane = tid & 63;
    const int quad = lane >> 4;
    const int l16  = lane & 15;
    const int wb   = wave * 16;

    // persistent weight fragments (live across all 4 windows)
    h8 aT[4], aV[4];
    for (int e0 = 0; e0 < 4; ++e0) {
        aT[e0] = *(const h8*)(Mt + (wb + l16) * 128 + e0 * 32 + quad * 8);
        const float* wp = Wv + (wb + l16) * 128 + e0 * 32 + quad * 8;
        f4 w0 = *(const f4*)(wp);
        f4 w1 = *(const f4*)(wp + 4);
        aV[e0] = (h8){(_Float16)w0.x, (_Float16)w0.y, (_Float16)w0.z, (_Float16)w0.w,
                      (_Float16)w1.x, (_Float16)w1.y, (_Float16)w1.z, (_Float16)w1.w};
    }
    f4 ck4  = *(const f4*)(ck + wb + quad * 4);
    float bvv = bv[wb + l16];

    const size_t base0 = (size_t)blockIdx.x * 4 * (128 * 128);

    // prefetch window 0 into registers
    f4 pf[8];
    for (int j = 0; j < 8; ++j)
        pf[j] = *(const f4*)(x + base0 + 4 * tid + 2048 * j);

    for (int it = 0; it < 4; ++it) {
        _Float16* X = Xs[it & 1];

        // ---- stage: convert prefetched regs -> X (f16 LDS) ----
        for (int j = 0; j < 8; ++j) {
            int idx = 4 * tid + 2048 * j;
            int row = idx >> 7, col = idx & 127;
            f4 f = pf[j];
            h4 h = {(_Float16)f.x, (_Float16)f.y, (_Float16)f.z, (_Float16)f.w};
            *(h4*)(&X[row * LDSP + col]) = h;
        }
        __syncthreads();  // X ready; also fences prev window's Ts/Vs readers

        // ---- issue prefetch for next window (completes during phases 1-2) ----
        if (it < 3) {
            const float* nx = x + base0 + (size_t)(it + 1) * (128 * 128);
            for (int j = 0; j < 8; ++j)
                pf[j] = *(const f4*)(nx + 4 * tid + 2048 * j);
        }

        // ---- phase 1: T'^T[f][w] = sum_e Mt[f][e] X[w][e] + ck_f ; V[u][d] ----
        {
            f4 accT[8], accV[8];
            for (int t = 0; t < 8; ++t) {
                accT[t] = ck4;
                accV[t] = (f4){bvv, bvv, bvv, bvv};
            }
            for (int e0 = 0; e0 < 4; ++e0) {
                h8 b[8];
                for (int nt = 0; nt < 8; ++nt)
                    b[nt] = *(const h8*)(&X[(nt * 16 + l16) * LDSP + e0 * 32 + quad * 8]);
                for (int nt = 0; nt < 8; ++nt) {
                    accT[nt] = __builtin_amdgcn_mfma_f32_16x16x32_f16(aT[e0], b[nt], accT[nt], 0, 0, 0);
                    accV[nt] = __builtin_amdgcn_mfma_f32_16x16x32_f16(b[nt], aV[e0], accV[nt], 0, 0, 0);
                }
            }
            // T' C/D: col = w = nt*16+l16, row = f = wb+quad*4+r -> packed write Ts[w][f]
            for (int nt = 0; nt < 8; ++nt) {
                f4 v = accT[nt];
                h4 h = {(_Float16)v.x, (_Float16)v.y, (_Float16)v.z, (_Float16)v.w};
                *(h4*)(&Ts[(nt * 16 + l16) * LDSP + wb + quad * 4]) = h;
                v = accV[nt];
                h4 g = {(_Float16)v.x, (_Float16)v.y, (_Float16)v.z, (_Float16)v.w};
                *(h4*)(&Vs[(wb + l16) * LDSP + nt * 16 + quad * 4]) = g;  // transposed: Vs[d][u]
            }
        }
        __syncthreads();  // Ts, Vs ready

        // ---- phase 2: S^T[u][w] = sum_f X[u][f] T'[w][f]; wave owns w-strip ----
        f4 acc[8];
        for (int mt = 0; mt < 8; ++mt) acc[mt] = (f4){0.f, 0.f, 0.f, 0.f};
        for (int f0 = 0; f0 < 4; ++f0) {
            h8 bt = *(const h8*)(&Ts[(wb + l16) * LDSP + f0 * 32 + quad * 8]);  // own strip only
            h8 a[8];
            for (int mt = 0; mt < 8; ++mt)
                a[mt] = *(const h8*)(&X[(mt * 16 + l16) * LDSP + f0 * 32 + quad * 8]);
            for (int mt = 0; mt < 8; ++mt)
                acc[mt] = __builtin_amdgcn_mfma_f32_16x16x32_f16(a[mt], bt, acc[mt], 0, 0, 0);
        }
        // softmax over u for lane's column w = wb+l16 (u spread across quads + mt tiles)
        {
            float m = -1e30f;
            for (int mt = 0; mt < 8; ++mt) {
                f4 v = acc[mt];
                m = fmaxf(m, fmaxf(fmaxf(v.x, v.y), fmaxf(v.z, v.w)));
            }
            m = fmaxf(m, __shfl_xor(m, 16, 64));
            m = fmaxf(m, __shfl_xor(m, 32, 64));
            float s = 0.f;
            for (int mt = 0; mt < 8; ++mt) {
                f4 v = acc[mt];
                v.x = __expf(v.x - m); v.y = __expf(v.y - m);
                v.z = __expf(v.z - m); v.w = __expf(v.w - m);
                acc[mt] = v;
                s += v.x + v.y + v.z + v.w;
            }
            s += __shfl_xor(s, 16, 64);
            s += __shfl_xor(s, 32, 64);
            float inv = 1.0f / s;
            // P quad-regs u-contiguous -> packed write into OWN strip of Ts (only this
            // wave ever reads Ts rows [wb,wb+16) in phases 2/3 -> no barrier needed)
            for (int mt = 0; mt < 8; ++mt) {
                f4 v = acc[mt];
                h4 h = {(_Float16)(v.x * inv), (_Float16)(v.y * inv),
                        (_Float16)(v.z * inv), (_Float16)(v.w * inv)};
                *(h4*)(&Ts[(wb + l16) * LDSP + mt * 16 + quad * 4]) = h;
            }
        }

        // ---- phase 3: O[w][d] = sum_u P[w][u] V[u][d] ----
        for (int nt = 0; nt < 8; ++nt) acc[nt] = (f4){0.f, 0.f, 0.f, 0.f};
        for (int u0 = 0; u0 < 4; ++u0) {
            h8 ap = *(const h8*)(&Ts[(wb + l16) * LDSP + u0 * 32 + quad * 8]);  // P own strip
            h8 b[8];
            for (int nt = 0; nt < 8; ++nt)
                b[nt] = *(const h8*)(&Vs[(nt * 16 + l16) * LDSP + u0 * 32 + quad * 8]);
            for (int nt = 0; nt < 8; ++nt)
                acc[nt] = __builtin_amdgcn_mfma_f32_16x16x32_f16(ap, b[nt], acc[nt], 0, 0, 0);
        }
        // C/D: col = d = nt*16+l16, row = w = wb+quad*4+r -> 64B-run coalesced stores
        float* ob = out + base0 + (size_t)it * (128 * 128);
        for (int nt = 0; nt < 8; ++nt) {
            f4 v = acc[nt];
            int w0 = wb + quad * 4;
            int d  = nt * 16 + l16;
            ob[(size_t)(w0 + 0) * 128 + d] = v.x;
            ob[(size_t)(w0 + 1) * 128 + d] = v.y;
            ob[(size_t)(w0 + 2) * 128 + d] = v.z;
            ob[(size_t)(w0 + 3) * 128 + d] = v.w;
        }
    }
}

extern "C" void kernel_launch(void* const* d_in, const int* in_sizes, int n_in,
                              void* d_out, int out_size, void* d_ws, size_t ws_size,
                              hipStream_t stream) {
    const float* x  = (const float*)d_in[0];
    const float* Wq = (const float*)d_in[1];
    const float* bq = (const float*)d_in[2];
    const float* Wk = (const float*)d_in[3];
    // bk (d_in[4]) drops out of softmax entirely
    const float* Wv = (const float*)d_in[5];
    const float* bv = (const float*)d_in[6];

    _Float16* Mt  = (_Float16*)d_ws;        // 32 KiB
    float*    ckp = (float*)(Mt + 16384);   // 512 B

    prep<<<64, 256, 0, stream>>>(Wq, Wk, bq, Mt, ckp);
    attn<<<256, 512, 0, stream>>>(x, Mt, Wv, ckp, bv, (float*)d_out);
}